// Round 16
// baseline (1308.404 us; speedup 1.0000x reference)
//
#include <hip/hip_runtime.h>
#include <stdint.h>

#define B    256
#define IU   8      // in_units (i)
#define JC   1152   // in_channels (j)
#define NN   10     // num_units (n)
#define UU   16     // unit_size (u)
#define NU   160    // NN*UU
#define JN   11520  // JC*NN
#define WROW 1280   // NN*UU*IU, floats per j in W
#define NP   9216   // IU*JC, x row length
#define KB   72     // k-split count (16 j per slice)
#define NBLK 512    // persistent grid (2 blocks/CU, co-resident by LDS/VGPR arithmetic)

typedef short bf16x8 __attribute__((ext_vector_type(8)));
typedef float f32x4  __attribute__((ext_vector_type(4)));

__device__ __forceinline__ short f2bf(float f) {
    union { float f; uint32_t u; } cv; cv.f = f;
    uint32_t u = cv.u;
    uint32_t r = u + 0x7fffu + ((u >> 16) & 1u);
    return (short)(r >> 16);
}
__device__ __forceinline__ float bf2f(short h) {
    union { uint32_t u; float f; } cv; cv.u = ((uint32_t)(unsigned short)h) << 16;
    return cv.f;
}
__device__ __forceinline__ uint32_t bfbits(float f) {
    union { float f; uint32_t u; } cv; cv.f = f;
    return (cv.u + 0x7fffu + ((cv.u >> 16) & 1u)) >> 16;
}
__device__ __forceinline__ uint32_t pk2(float a, float b) {
    return bfbits(a) | (bfbits(b) << 16);
}

// grid barrier: one arrive + one spinner per block; device-scope atomics +
// threadfence release/acquire (cross-XCD coherent per G16/m20).
__device__ __forceinline__ void gbar(int* bar, int idx) {
    __syncthreads();
    if (threadIdx.x == 0) {
        __threadfence();
        __hip_atomic_fetch_add(&bar[idx * 32], 1, __ATOMIC_RELEASE,
                               __HIP_MEMORY_SCOPE_AGENT);
        while (__hip_atomic_load(&bar[idx * 32], __ATOMIC_ACQUIRE,
                                 __HIP_MEMORY_SCOPE_AGENT) < NBLK)
            __builtin_amdgcn_s_sleep(2);
        __threadfence();
    }
    __syncthreads();
}

__global__ void __launch_bounds__(256, 2)
k_capsule(const float* xg, const float* wg, float* out,
          float* blog, float* cbuf, float* db, float* v,
          float* s_part, float* G, int* bar) {
    const int bid = blockIdx.x;
    const int tid = threadIdx.x;
    const int wv = tid >> 6, lane = tid & 63;
    const int q = lane >> 4, l16 = lane & 15;
    __shared__ __align__(16) char smem[24576];
    int bi = 0;

    for (int t = 0; t < 3; ++t) {
        // ================= phase 1: gemm1, 576 units (kb, mt) ===========
        {
            short* As = (short*)smem;            // 8*32*8 = 4 KB
            short* Bs = (short*)(smem + 4096);   // 8*160*8 = 20 KB
            const int mfrag = wv >> 1;
            const int ntb = (wv & 1) * 5;
            for (int u = bid; u < 576; u += NBLK) {
                const int kb = u >> 3, mt = u & 7;
                const int b0 = mt * 32, jb0 = kb * 16;
                f32x4 acc[5];
                #pragma unroll
                for (int nt = 0; nt < 5; ++nt) acc[nt] = (f32x4){0.f,0.f,0.f,0.f};
                for (int jc = 0; jc < 2; ++jc) {
                    const int j0 = jb0 + jc * 8;
                    __syncthreads();
                    #pragma unroll
                    for (int p = 0; p < 2; ++p) {
                        int idx = tid + 256 * p;
                        int jq = idx & 1;
                        int row = idx >> 1;
                        int bl = row >> 3, ii = row & 7;
                        const float4 xv = *reinterpret_cast<const float4*>(
                            &xg[(size_t)(b0 + bl) * NP + ii * JC + j0 + jq*4]);
                        int jjb = jq * 4;
                        As[((jjb+0)*32 + bl)*8 + ii] = f2bf(xv.x);
                        As[((jjb+1)*32 + bl)*8 + ii] = f2bf(xv.y);
                        As[((jjb+2)*32 + bl)*8 + ii] = f2bf(xv.z);
                        As[((jjb+3)*32 + bl)*8 + ii] = f2bf(xv.w);
                    }
                    #pragma unroll
                    for (int p = 0; p < 5; ++p) {
                        int ridx = tid + 256 * p;
                        int jj = ridx / 160;
                        int nu = ridx - jj * 160;
                        int j  = j0 + jj;
                        const float4* wp = reinterpret_cast<const float4*>(
                            &wg[(size_t)j * WROW + (size_t)nu * 8]);
                        float4 f0 = wp[0], f1 = wp[1];
                        float cc = (t == 0) ? (1.0f / (float)JC)
                                            : cbuf[j * NN + (nu >> 4)];
                        uint4 d;
                        d.x = pk2(f0.x * cc, f0.y * cc);
                        d.y = pk2(f0.z * cc, f0.w * cc);
                        d.z = pk2(f1.x * cc, f1.y * cc);
                        d.w = pk2(f1.z * cc, f1.w * cc);
                        *reinterpret_cast<uint4*>(&Bs[(size_t)ridx * 8]) = d;
                    }
                    __syncthreads();
                    #pragma unroll
                    for (int s = 0; s < 2; ++s) {
                        int jj = s*4 + q;
                        bf16x8 av = *reinterpret_cast<const bf16x8*>(
                            &As[((jj*32 + mfrag*16 + l16) << 3)]);
                        #pragma unroll
                        for (int nt = 0; nt < 5; ++nt) {
                            bf16x8 bv = *reinterpret_cast<const bf16x8*>(
                                &Bs[((jj*160 + (ntb + nt)*16 + l16) << 3)]);
                            acc[nt] = __builtin_amdgcn_mfma_f32_16x16x32_bf16(
                                av, bv, acc[nt], 0, 0, 0);
                        }
                    }
                }
                float* dst = s_part + (size_t)(kb*8 + mt) * 5120;
                #pragma unroll
                for (int nt = 0; nt < 5; ++nt)
                    #pragma unroll
                    for (int reg = 0; reg < 4; ++reg)
                        dst[(mfrag*16 + q*4 + reg) * 160 + (ntb + nt)*16 + l16]
                            = acc[nt][reg];
            }
        }
        gbar(bar, bi++);

        // ================= phase 2: reduce + squash, 256 units (b) ======
        {
            float* sv = (float*)smem;
            float* fb = sv + NU;
            if (bid < 256) {
                const int b = bid;
                const int mt = b >> 5, bl = b & 31;
                __syncthreads();
                if (tid < NU) {
                    const size_t off = (size_t)mt * 5120 + bl * 160 + tid;
                    float s = 0.f;
                    for (int r = 0; r < KB; ++r)
                        s += s_part[(size_t)r * 40960 + off];
                    sv[tid] = s;
                }
                __syncthreads();
                if (tid < UU) {
                    float m = 0.f;
                    #pragma unroll
                    for (int n = 0; n < NN; ++n) {
                        float z = sv[n*16 + tid]; m = fmaf(z, z, m);
                    }
                    fb[tid] = sqrtf(m) / (1.f + m);
                }
                __syncthreads();
                float* vdst = (t == 2) ? out : v;
                if (tid < NU)
                    vdst[(size_t)b * NU + tid] = sv[tid] * fb[tid & 15];
            }
        }
        if (t == 2) break;   // final output written; all blocks just exit
        gbar(bar, bi++);

        // ================= phase 3: vxg, 720 units (np-tile, m-tile) ====
        {
            short* Ash = (short*)smem;              // 4 KB
            short* Asl = (short*)(smem + 4096);     // 4 KB
            short* Bsh = (short*)(smem + 8192);     // 8 KB
            short* Bsl = (short*)(smem + 16384);    // 8 KB
            for (int u = bid; u < 720; u += NBLK) {
                const int np0 = (u % 144) * 64, m0 = (u / 144) * 32;
                f32x4 acc2[2];
                acc2[0] = (f32x4){0.f,0.f,0.f,0.f};
                acc2[1] = (f32x4){0.f,0.f,0.f,0.f};
                for (int ks = 0; ks < 4; ++ks) {
                    const int b0 = ks * 64;
                    __syncthreads();
                    #pragma unroll
                    for (int p = 0; p < 8; ++p) {
                        int idx = tid + 256 * p;
                        int bb = idx >> 5, ml = idx & 31;
                        float vv = v[(size_t)(b0 + bb) * NU + m0 + ml];
                        short hi = f2bf(vv);
                        short lo = f2bf(vv - bf2f(hi));
                        int a = ((bb >> 3) * 32 + ml) * 8 + (bb & 7);
                        Ash[a] = hi; Asl[a] = lo;
                    }
                    #pragma unroll
                    for (int p = 0; p < 16; ++p) {
                        int idx = tid + 256 * p;
                        int bb = idx >> 6, nl = idx & 63;
                        float xv = xg[(size_t)(b0 + bb) * NP + np0 + nl];
                        short hi = f2bf(xv);
                        short lo = f2bf(xv - bf2f(hi));
                        int a = ((bb >> 3) * 64 + nl) * 8 + (bb & 7);
                        Bsh[a] = hi; Bsl[a] = lo;
                    }
                    __syncthreads();
                    #pragma unroll
                    for (int s = 0; s < 2; ++s) {
                        int kc = s*4 + q;
                        bf16x8 bh = *reinterpret_cast<const bf16x8*>(
                            &Bsh[((kc*64 + wv*16 + l16) << 3)]);
                        bf16x8 bl = *reinterpret_cast<const bf16x8*>(
                            &Bsl[((kc*64 + wv*16 + l16) << 3)]);
                        #pragma unroll
                        for (int mtl = 0; mtl < 2; ++mtl) {
                            bf16x8 ah = *reinterpret_cast<const bf16x8*>(
                                &Ash[((kc*32 + mtl*16 + l16) << 3)]);
                            bf16x8 al = *reinterpret_cast<const bf16x8*>(
                                &Asl[((kc*32 + mtl*16 + l16) << 3)]);
                            acc2[mtl] = __builtin_amdgcn_mfma_f32_16x16x32_bf16(
                                ah, bh, acc2[mtl], 0, 0, 0);
                            acc2[mtl] = __builtin_amdgcn_mfma_f32_16x16x32_bf16(
                                ah, bl, acc2[mtl], 0, 0, 0);
                            acc2[mtl] = __builtin_amdgcn_mfma_f32_16x16x32_bf16(
                                al, bh, acc2[mtl], 0, 0, 0);
                        }
                    }
                }
                #pragma unroll
                for (int mtl = 0; mtl < 2; ++mtl)
                    #pragma unroll
                    for (int reg = 0; reg < 4; ++reg) {
                        int m = m0 + mtl*16 + q*4 + reg;
                        G[(size_t)m * NP + np0 + wv*16 + l16] = acc2[mtl][reg];
                    }
            }
        }
        gbar(bar, bi++);

        // ================= phase 4: wg_db, 180 units (j-tile, n) ========
        {
            float* red = (float*)smem;   // 4*64 floats
            for (int u = bid; u < 180; u += NBLK) {
                const int j0 = (u / 10) * 64, n = u % 10;
                const int jl = tid & 63, up = tid >> 6;
                const int j = j0 + jl;
                __syncthreads();
                const float4* wp = reinterpret_cast<const float4*>(
                    wg + (size_t)j * WROW + n * 128 + up * 32);
                float acc = 0.f;
                #pragma unroll
                for (int q4 = 0; q4 < 4; ++q4) {
                    int uu = up*4 + q4;
                    const float* gp = G + (size_t)(n*16 + uu) * NP + j;
                    float4 w0 = wp[q4*2], w1 = wp[q4*2 + 1];
                    acc = fmaf(w0.x, gp[0*JC], acc);
                    acc = fmaf(w0.y, gp[1*JC], acc);
                    acc = fmaf(w0.z, gp[2*JC], acc);
                    acc = fmaf(w0.w, gp[3*JC], acc);
                    acc = fmaf(w1.x, gp[4*JC], acc);
                    acc = fmaf(w1.y, gp[5*JC], acc);
                    acc = fmaf(w1.z, gp[6*JC], acc);
                    acc = fmaf(w1.w, gp[7*JC], acc);
                }
                red[up*64 + jl] = acc;
                __syncthreads();
                if (tid < 64)
                    db[(size_t)(j0 + tid) * NN + n] =
                        red[0*64+tid] + red[1*64+tid] + red[2*64+tid] + red[3*64+tid];
            }
        }
        gbar(bar, bi++);

        // ================= phase 5: blog update + softmax, 10 units =====
        {
            float* red = (float*)smem;   // 256 floats
            if (bid < NN) {
                const int n = bid;
                const int j1 = tid + 256, j2 = tid + 512, j3 = tid + 768,
                          j4 = tid + 1024;
                const bool h4 = (j4 < JC);
                __syncthreads();
                float a0, a1, a2, a3, a4;
                {
                    float d0 = db[tid*NN + n] * (1.f / (float)B);
                    float d1 = db[j1*NN + n] * (1.f / (float)B);
                    float d2 = db[j2*NN + n] * (1.f / (float)B);
                    float d3 = db[j3*NN + n] * (1.f / (float)B);
                    float d4 = h4 ? db[j4*NN + n] * (1.f / (float)B) : 0.f;
                    if (t == 0) { a0 = d0; a1 = d1; a2 = d2; a3 = d3; a4 = d4; }
                    else {
                        a0 = blog[tid*NN + n] + d0;
                        a1 = blog[j1*NN + n] + d1;
                        a2 = blog[j2*NN + n] + d2;
                        a3 = blog[j3*NN + n] + d3;
                        a4 = h4 ? blog[j4*NN + n] + d4 : 0.f;
                    }
                }
                blog[tid*NN + n] = a0; blog[j1*NN + n] = a1;
                blog[j2*NN + n] = a2;  blog[j3*NN + n] = a3;
                if (h4) blog[j4*NN + n] = a4;

                float m = fmaxf(fmaxf(a0, a1), fmaxf(a2, a3));
                if (h4) m = fmaxf(m, a4);
                red[tid] = m; __syncthreads();
                for (int s = 128; s > 0; s >>= 1) {
                    if (tid < s) red[tid] = fmaxf(red[tid], red[tid+s]);
                    __syncthreads();
                }
                m = red[0]; __syncthreads();
                float e0 = __expf(a0 - m), e1 = __expf(a1 - m),
                      e2 = __expf(a2 - m), e3 = __expf(a3 - m),
                      e4 = h4 ? __expf(a4 - m) : 0.f;
                red[tid] = e0 + e1 + e2 + e3 + e4; __syncthreads();
                for (int s = 128; s > 0; s >>= 1) {
                    if (tid < s) red[tid] += red[tid+s];
                    __syncthreads();
                }
                float inv = 1.f / red[0];
                cbuf[tid*NN + n] = e0 * inv;
                cbuf[j1*NN + n] = e1 * inv;
                cbuf[j2*NN + n] = e2 * inv;
                cbuf[j3*NN + n] = e3 * inv;
                if (h4) cbuf[j4*NN + n] = e4 * inv;
            }
        }
        gbar(bar, bi++);
    }
}

extern "C" void kernel_launch(void* const* d_in, const int* in_sizes, int n_in,
                              void* d_out, int out_size, void* d_ws, size_t ws_size,
                              hipStream_t stream) {
    const float* x = (const float*)d_in[0];
    const float* w = (const float*)d_in[1];
    float* out = (float*)d_out;

    float* ws     = (float*)d_ws;
    float* blog   = ws;                           // 11520
    float* c      = blog + JN;                    // 11520
    float* db     = c + JN;                       // 11520
    float* v      = db + JN;                      // 40960
    float* s_part = v + (size_t)B*NU;             // 72*40960 = 2,949,120
    float* G      = s_part + (size_t)KB * 40960;  // 1,474,560
    int*   bar    = (int*)(G + 1474560);          // 11*32 ints
    // total ≈ 17.9 MB

    hipMemsetAsync(bar, 0, 16 * 32 * sizeof(int), stream);
    k_capsule<<<NBLK, 256, 0, stream>>>(x, w, out, blog, c, db, v, s_part, G, bar);
}

// Round 17
// 1146.420 us; speedup vs baseline: 1.1413x; 1.1413x over previous
//
#include <hip/hip_runtime.h>
#include <stdint.h>

#define B    256
#define IU   8      // in_units (i)
#define JC   1152   // in_channels (j)
#define NN   10     // num_units (n)
#define UU   16     // unit_size (u)
#define NU   160    // NN*UU
#define JN   11520  // JC*NN
#define WROW 1280   // NN*UU*IU, floats per j in W
#define NP   9216   // IU*JC, x row length
#define KB   72     // k-split count (16 j per slice)
#define NBLK 720    // persistent grid; capacity 4 blk/CU (VGPR<=128) >= 720

typedef short bf16x8 __attribute__((ext_vector_type(8)));
typedef float f32x4  __attribute__((ext_vector_type(4)));

__device__ __forceinline__ short f2bf(float f) {
    union { float f; uint32_t u; } cv; cv.f = f;
    uint32_t u = cv.u;
    uint32_t r = u + 0x7fffu + ((u >> 16) & 1u);
    return (short)(r >> 16);
}
__device__ __forceinline__ float bf2f(short h) {
    union { uint32_t u; float f; } cv; cv.u = ((uint32_t)(unsigned short)h) << 16;
    return cv.f;
}
__device__ __forceinline__ uint32_t bfbits(float f) {
    union { float f; uint32_t u; } cv; cv.f = f;
    return (cv.u + 0x7fffu + ((cv.u >> 16) & 1u)) >> 16;
}
__device__ __forceinline__ uint32_t pk2(float a, float b) {
    return bfbits(a) | (bfbits(b) << 16);
}

// Two-stage grid barrier. Polls are RELAXED memory-side RMWs (fetch_add 0):
// no per-poll cache invalidation (the R16 bug). Release fences are clustered
// after stage A (when all blocks have finished phase work), so L2 writebacks
// never trash a still-computing laggard's cache.
__device__ __forceinline__ void gbar(int* bar, int idx) {
    __syncthreads();
    if (threadIdx.x == 0) {
        int* A = &bar[(2*idx)   * 32];
        int* C = &bar[(2*idx+1) * 32];
        __hip_atomic_fetch_add(A, 1, __ATOMIC_RELAXED, __HIP_MEMORY_SCOPE_AGENT);
        while (__hip_atomic_fetch_add(A, 0, __ATOMIC_RELAXED,
                                      __HIP_MEMORY_SCOPE_AGENT) < NBLK)
            __builtin_amdgcn_s_sleep(8);
        __threadfence();   // release: flush this XCD's dirty lines (clustered)
        __hip_atomic_fetch_add(C, 1, __ATOMIC_RELAXED, __HIP_MEMORY_SCOPE_AGENT);
        while (__hip_atomic_fetch_add(C, 0, __ATOMIC_RELAXED,
                                      __HIP_MEMORY_SCOPE_AGENT) < NBLK)
            __builtin_amdgcn_s_sleep(8);
        __threadfence();   // acquire: invalidate so we read others' data
    }
    __syncthreads();
}

__global__ void __launch_bounds__(256, 4)
k_capsule(const float* xg, const float* wg, float* out,
          float* blog, float* cbuf, float* db, float* v,
          float* s_part, float* G, int* bar) {
    const int bid = blockIdx.x;
    const int tid = threadIdx.x;
    const int wv = tid >> 6, lane = tid & 63;
    const int q = lane >> 4, l16 = lane & 15;
    __shared__ __align__(16) char smem[24576];
    int bi = 0;

    for (int t = 0; t < 3; ++t) {
        // ===== phase 1: gemm1, 576 units (kb, mt) — one unit per block ====
        if (bid < 576) {
            short* As = (short*)smem;            // 4 KB
            short* Bs = (short*)(smem + 4096);   // 20 KB
            const int mfrag = wv >> 1;
            const int ntb = (wv & 1) * 5;
            const int kb = bid >> 3, mt = bid & 7;
            const int b0 = mt * 32, jb0 = kb * 16;
            f32x4 acc[5];
            #pragma unroll
            for (int nt = 0; nt < 5; ++nt) acc[nt] = (f32x4){0.f,0.f,0.f,0.f};
            for (int jc = 0; jc < 2; ++jc) {
                const int j0 = jb0 + jc * 8;
                __syncthreads();
                #pragma unroll
                for (int p = 0; p < 2; ++p) {
                    int idx = tid + 256 * p;
                    int jq = idx & 1;
                    int row = idx >> 1;
                    int bl = row >> 3, ii = row & 7;
                    const float4 xv = *reinterpret_cast<const float4*>(
                        &xg[(size_t)(b0 + bl) * NP + ii * JC + j0 + jq*4]);
                    int jjb = jq * 4;
                    As[((jjb+0)*32 + bl)*8 + ii] = f2bf(xv.x);
                    As[((jjb+1)*32 + bl)*8 + ii] = f2bf(xv.y);
                    As[((jjb+2)*32 + bl)*8 + ii] = f2bf(xv.z);
                    As[((jjb+3)*32 + bl)*8 + ii] = f2bf(xv.w);
                }
                #pragma unroll
                for (int p = 0; p < 5; ++p) {
                    int ridx = tid + 256 * p;
                    int jj = ridx / 160;
                    int nu = ridx - jj * 160;
                    int j  = j0 + jj;
                    const float4* wp = reinterpret_cast<const float4*>(
                        &wg[(size_t)j * WROW + (size_t)nu * 8]);
                    float4 f0 = wp[0], f1 = wp[1];
                    float cc = (t == 0) ? (1.0f / (float)JC)
                                        : cbuf[j * NN + (nu >> 4)];
                    uint4 d;
                    d.x = pk2(f0.x * cc, f0.y * cc);
                    d.y = pk2(f0.z * cc, f0.w * cc);
                    d.z = pk2(f1.x * cc, f1.y * cc);
                    d.w = pk2(f1.z * cc, f1.w * cc);
                    *reinterpret_cast<uint4*>(&Bs[(size_t)ridx * 8]) = d;
                }
                __syncthreads();
                #pragma unroll
                for (int s = 0; s < 2; ++s) {
                    int jj = s*4 + q;
                    bf16x8 av = *reinterpret_cast<const bf16x8*>(
                        &As[((jj*32 + mfrag*16 + l16) << 3)]);
                    #pragma unroll
                    for (int nt = 0; nt < 5; ++nt) {
                        bf16x8 bv = *reinterpret_cast<const bf16x8*>(
                            &Bs[((jj*160 + (ntb + nt)*16 + l16) << 3)]);
                        acc[nt] = __builtin_amdgcn_mfma_f32_16x16x32_bf16(
                            av, bv, acc[nt], 0, 0, 0);
                    }
                }
            }
            float* dst = s_part + (size_t)(kb*8 + mt) * 5120;
            #pragma unroll
            for (int nt = 0; nt < 5; ++nt)
                #pragma unroll
                for (int reg = 0; reg < 4; ++reg)
                    dst[(mfrag*16 + q*4 + reg) * 160 + (ntb + nt)*16 + l16]
                        = acc[nt][reg];
        }
        gbar(bar, bi++);

        // ===== phase 2: reduce + squash, 256 units (b) ====================
        if (bid < 256) {
            float* sv = (float*)smem;
            float* fb = sv + NU;
            const int b = bid;
            const int mt = b >> 5, bl = b & 31;
            __syncthreads();
            if (tid < NU) {
                const size_t off = (size_t)mt * 5120 + bl * 160 + tid;
                float s = 0.f;
                for (int r = 0; r < KB; ++r)
                    s += s_part[(size_t)r * 40960 + off];
                sv[tid] = s;
            }
            __syncthreads();
            if (tid < UU) {
                float m = 0.f;
                #pragma unroll
                for (int n = 0; n < NN; ++n) {
                    float z = sv[n*16 + tid]; m = fmaf(z, z, m);
                }
                fb[tid] = sqrtf(m) / (1.f + m);
            }
            __syncthreads();
            float* vdst = (t == 2) ? out : v;
            if (tid < NU)
                vdst[(size_t)b * NU + tid] = sv[tid] * fb[tid & 15];
        }
        if (t == 2) break;   // final output written; kernel-end fence handles it
        gbar(bar, bi++);

        // ===== phase 3: vxg, 720 units — exactly one per block ============
        {
            short* Ash = (short*)smem;              // 4 KB
            short* Asl = (short*)(smem + 4096);     // 4 KB
            short* Bsh = (short*)(smem + 8192);     // 8 KB
            short* Bsl = (short*)(smem + 16384);    // 8 KB
            const int np0 = (bid % 144) * 64, m0 = (bid / 144) * 32;
            f32x4 acc2[2];
            acc2[0] = (f32x4){0.f,0.f,0.f,0.f};
            acc2[1] = (f32x4){0.f,0.f,0.f,0.f};
            for (int ks = 0; ks < 4; ++ks) {
                const int b0 = ks * 64;
                __syncthreads();
                #pragma unroll
                for (int p = 0; p < 8; ++p) {
                    int idx = tid + 256 * p;
                    int bb = idx >> 5, ml = idx & 31;
                    float vv = v[(size_t)(b0 + bb) * NU + m0 + ml];
                    short hi = f2bf(vv);
                    short lo = f2bf(vv - bf2f(hi));
                    int a = ((bb >> 3) * 32 + ml) * 8 + (bb & 7);
                    Ash[a] = hi; Asl[a] = lo;
                }
                #pragma unroll
                for (int p = 0; p < 16; ++p) {
                    int idx = tid + 256 * p;
                    int bb = idx >> 6, nl = idx & 63;
                    float xv = xg[(size_t)(b0 + bb) * NP + np0 + nl];
                    short hi = f2bf(xv);
                    short lo = f2bf(xv - bf2f(hi));
                    int a = ((bb >> 3) * 64 + nl) * 8 + (bb & 7);
                    Bsh[a] = hi; Bsl[a] = lo;
                }
                __syncthreads();
                #pragma unroll
                for (int s = 0; s < 2; ++s) {
                    int kc = s*4 + q;
                    bf16x8 bh = *reinterpret_cast<const bf16x8*>(
                        &Bsh[((kc*64 + wv*16 + l16) << 3)]);
                    bf16x8 bl = *reinterpret_cast<const bf16x8*>(
                        &Bsl[((kc*64 + wv*16 + l16) << 3)]);
                    #pragma unroll
                    for (int mtl = 0; mtl < 2; ++mtl) {
                        bf16x8 ah = *reinterpret_cast<const bf16x8*>(
                            &Ash[((kc*32 + mtl*16 + l16) << 3)]);
                        bf16x8 al = *reinterpret_cast<const bf16x8*>(
                            &Asl[((kc*32 + mtl*16 + l16) << 3)]);
                        acc2[mtl] = __builtin_amdgcn_mfma_f32_16x16x32_bf16(
                            ah, bh, acc2[mtl], 0, 0, 0);
                        acc2[mtl] = __builtin_amdgcn_mfma_f32_16x16x32_bf16(
                            ah, bl, acc2[mtl], 0, 0, 0);
                        acc2[mtl] = __builtin_amdgcn_mfma_f32_16x16x32_bf16(
                            al, bh, acc2[mtl], 0, 0, 0);
                    }
                }
            }
            #pragma unroll
            for (int mtl = 0; mtl < 2; ++mtl)
                #pragma unroll
                for (int reg = 0; reg < 4; ++reg) {
                    int m = m0 + mtl*16 + q*4 + reg;
                    G[(size_t)m * NP + np0 + wv*16 + l16] = acc2[mtl][reg];
                }
        }
        gbar(bar, bi++);

        // ===== phase 4: wg_db, 180 units (j-tile, n) ======================
        if (bid < 180) {
            float* red = (float*)smem;   // 4*64 floats
            const int j0 = (bid / 10) * 64, n = bid % 10;
            const int jl = tid & 63, up = tid >> 6;
            const int j = j0 + jl;
            __syncthreads();
            const float4* wp = reinterpret_cast<const float4*>(
                wg + (size_t)j * WROW + n * 128 + up * 32);
            float acc = 0.f;
            #pragma unroll
            for (int q4 = 0; q4 < 4; ++q4) {
                int uu = up*4 + q4;
                const float* gp = G + (size_t)(n*16 + uu) * NP + j;
                float4 w0 = wp[q4*2], w1 = wp[q4*2 + 1];
                acc = fmaf(w0.x, gp[0*JC], acc);
                acc = fmaf(w0.y, gp[1*JC], acc);
                acc = fmaf(w0.z, gp[2*JC], acc);
                acc = fmaf(w0.w, gp[3*JC], acc);
                acc = fmaf(w1.x, gp[4*JC], acc);
                acc = fmaf(w1.y, gp[5*JC], acc);
                acc = fmaf(w1.z, gp[6*JC], acc);
                acc = fmaf(w1.w, gp[7*JC], acc);
            }
            red[up*64 + jl] = acc;
            __syncthreads();
            if (tid < 64)
                db[(size_t)(j0 + tid) * NN + n] =
                    red[0*64+tid] + red[1*64+tid] + red[2*64+tid] + red[3*64+tid];
        }
        gbar(bar, bi++);

        // ===== phase 5: blog update + softmax, 10 units ===================
        if (bid < NN) {
            float* red = (float*)smem;   // 256 floats
            const int n = bid;
            const int j1 = tid + 256, j2 = tid + 512, j3 = tid + 768,
                      j4 = tid + 1024;
            const bool h4 = (j4 < JC);
            __syncthreads();
            float a0, a1, a2, a3, a4;
            {
                float d0 = db[tid*NN + n] * (1.f / (float)B);
                float d1 = db[j1*NN + n] * (1.f / (float)B);
                float d2 = db[j2*NN + n] * (1.f / (float)B);
                float d3 = db[j3*NN + n] * (1.f / (float)B);
                float d4 = h4 ? db[j4*NN + n] * (1.f / (float)B) : 0.f;
                if (t == 0) { a0 = d0; a1 = d1; a2 = d2; a3 = d3; a4 = d4; }
                else {
                    a0 = blog[tid*NN + n] + d0;
                    a1 = blog[j1*NN + n] + d1;
                    a2 = blog[j2*NN + n] + d2;
                    a3 = blog[j3*NN + n] + d3;
                    a4 = h4 ? blog[j4*NN + n] + d4 : 0.f;
                }
            }
            blog[tid*NN + n] = a0; blog[j1*NN + n] = a1;
            blog[j2*NN + n] = a2;  blog[j3*NN + n] = a3;
            if (h4) blog[j4*NN + n] = a4;

            float m = fmaxf(fmaxf(a0, a1), fmaxf(a2, a3));
            if (h4) m = fmaxf(m, a4);
            red[tid] = m; __syncthreads();
            for (int s = 128; s > 0; s >>= 1) {
                if (tid < s) red[tid] = fmaxf(red[tid], red[tid+s]);
                __syncthreads();
            }
            m = red[0]; __syncthreads();
            float e0 = __expf(a0 - m), e1 = __expf(a1 - m),
                  e2 = __expf(a2 - m), e3 = __expf(a3 - m),
                  e4 = h4 ? __expf(a4 - m) : 0.f;
            red[tid] = e0 + e1 + e2 + e3 + e4; __syncthreads();
            for (int s = 128; s > 0; s >>= 1) {
                if (tid < s) red[tid] += red[tid+s];
                __syncthreads();
            }
            float inv = 1.f / red[0];
            cbuf[tid*NN + n] = e0 * inv;
            cbuf[j1*NN + n] = e1 * inv;
            cbuf[j2*NN + n] = e2 * inv;
            cbuf[j3*NN + n] = e3 * inv;
            if (h4) cbuf[j4*NN + n] = e4 * inv;
        }
        gbar(bar, bi++);
    }
}

extern "C" void kernel_launch(void* const* d_in, const int* in_sizes, int n_in,
                              void* d_out, int out_size, void* d_ws, size_t ws_size,
                              hipStream_t stream) {
    const float* x = (const float*)d_in[0];
    const float* w = (const float*)d_in[1];
    float* out = (float*)d_out;

    float* ws     = (float*)d_ws;
    float* blog   = ws;                           // 11520
    float* c      = blog + JN;                    // 11520
    float* db     = c + JN;                       // 11520
    float* v      = db + JN;                      // 40960
    float* s_part = v + (size_t)B*NU;             // 72*40960 = 2,949,120
    float* G      = s_part + (size_t)KB * 40960;  // 1,474,560
    int*   bar    = (int*)(G + 1474560);          // 22 counters x 32-int stride
    // total ≈ 17.9 MB

    hipMemsetAsync(bar, 0, 64 * 32 * sizeof(int), stream);
    k_capsule<<<NBLK, 256, 0, stream>>>(x, w, out, blog, c, db, v, s_part, G, bar);
}

// Round 18
// 151.538 us; speedup vs baseline: 8.6341x; 7.5652x over previous
//
#include <hip/hip_runtime.h>
#include <stdint.h>

#define B   256
#define IU  8      // in_units (i)
#define JC  1152   // in_channels (j)
#define NN  10     // num_units (n)
#define UU  16     // unit_size (u)
#define NU  160    // NN*UU
#define JN  11520  // JC*NN
#define WROW 1280  // NN*UU*IU, floats per j in W
#define NP  9216   // IU*JC, x row length
#define KB  72     // k-split count (16 j per slice, 2 chunks of 8)

typedef short bf16x8 __attribute__((ext_vector_type(8)));
typedef float f32x4  __attribute__((ext_vector_type(4)));

__device__ __forceinline__ short f2bf(float f) {
    union { float f; uint32_t u; } cv; cv.f = f;
    uint32_t u = cv.u;
    uint32_t r = u + 0x7fffu + ((u >> 16) & 1u);
    return (short)(r >> 16);
}
__device__ __forceinline__ float bf2f(short h) {
    union { uint32_t u; float f; } cv; cv.u = ((uint32_t)(unsigned short)h) << 16;
    return cv.f;
}
__device__ __forceinline__ uint32_t bfbits(float f) {
    union { float f; uint32_t u; } cv; cv.f = f;
    return (cv.u + 0x7fffu + ((cv.u >> 16) & 1u)) >> 16;
}
__device__ __forceinline__ uint32_t pk2(float a, float b) {
    return bfbits(a) | (bfbits(b) << 16);
}

// ---------------- pass 1 MFMA GEMM: s = x[256,9216] * (c*W)^T ------------
// grid (KB=72 k-splits of 16 j, 8 m-tiles of 32 b) = 576 blocks; 4 waves.
// Wave wv: m-frag = wv>>1 (16 b), nu-half = (wv&1)*5 tiles. LDS 24 KB.
// Slice commit: s_part[kb*8+mt][b_local(32)][nu(160)] dense.
__global__ void __launch_bounds__(256, 2)
k_gemm1(const float* __restrict__ xg, const float* __restrict__ wg,
        const float* __restrict__ cptr, float* __restrict__ s_part) {
    const int kb = blockIdx.x, mt = blockIdx.y;
    const int tid = threadIdx.x;
    const int wv = tid >> 6, lane = tid & 63;
    const int q = lane >> 4, l16 = lane & 15;
    const int b0 = mt * 32;
    const int jb0 = kb * 16;
    const int mfrag = wv >> 1;          // 0..1
    const int ntb = (wv & 1) * 5;       // 0 or 5

    __shared__ __align__(16) short As[8 * 32 * 8];   // 4 KB  [jj][bl][ii]
    __shared__ __align__(16) short Bs[8 * 160 * 8];  // 20 KB [jj][nu][ii]

    f32x4 acc[5];
    #pragma unroll
    for (int nt = 0; nt < 5; ++nt) acc[nt] = (f32x4){0.f, 0.f, 0.f, 0.f};

    for (int jc = 0; jc < 2; ++jc) {
        const int j0 = jb0 + jc * 8;
        __syncthreads();
        // stage As: x[b0+bl][ii][j0+jj] -> As[jj][bl][ii]  (512 float4s)
        #pragma unroll
        for (int p = 0; p < 2; ++p) {
            int idx = tid + 256 * p;        // 0..511
            int jq  = idx & 1;
            int row = idx >> 1;             // bl*8+ii
            int bl = row >> 3, ii = row & 7;
            const float4 xv = *reinterpret_cast<const float4*>(
                &xg[(size_t)(b0 + bl) * NP + ii * JC + j0 + jq*4]);
            int jjb = jq * 4;
            As[((jjb+0)*32 + bl)*8 + ii] = f2bf(xv.x);
            As[((jjb+1)*32 + bl)*8 + ii] = f2bf(xv.y);
            As[((jjb+2)*32 + bl)*8 + ii] = f2bf(xv.z);
            As[((jjb+3)*32 + bl)*8 + ii] = f2bf(xv.w);
        }
        // stage Bs: one W row (8 i, 32B contig) -> one ds_write_b128
        #pragma unroll
        for (int p = 0; p < 5; ++p) {
            int ridx = tid + 256 * p;       // 0..1279 = jj*160+nu
            int jj = ridx / 160;
            int nu = ridx - jj * 160;
            int j  = j0 + jj;
            const float4* wp = reinterpret_cast<const float4*>(
                &wg[(size_t)j * WROW + (size_t)nu * 8]);
            float4 f0 = wp[0], f1 = wp[1];
            float cc = cptr ? cptr[j * NN + (nu >> 4)] : (1.0f / (float)JC);
            uint4 d;
            d.x = pk2(f0.x * cc, f0.y * cc);
            d.y = pk2(f0.z * cc, f0.w * cc);
            d.z = pk2(f1.x * cc, f1.y * cc);
            d.w = pk2(f1.z * cc, f1.w * cc);
            *reinterpret_cast<uint4*>(&Bs[(size_t)ridx * 8]) = d;
        }
        __syncthreads();
        #pragma unroll
        for (int s = 0; s < 2; ++s) {
            int jj = s*4 + q;
            bf16x8 av = *reinterpret_cast<const bf16x8*>(
                &As[((jj*32 + mfrag*16 + l16) << 3)]);
            #pragma unroll
            for (int nt = 0; nt < 5; ++nt) {
                bf16x8 bv = *reinterpret_cast<const bf16x8*>(
                    &Bs[((jj*160 + (ntb + nt)*16 + l16) << 3)]);
                acc[nt] = __builtin_amdgcn_mfma_f32_16x16x32_bf16(av, bv, acc[nt], 0, 0, 0);
            }
        }
    }
    // commit: b_local = mfrag*16 + q*4 + reg, nu = (ntb+nt)*16 + l16
    float* dst = s_part + (size_t)(kb*8 + mt) * 5120;
    #pragma unroll
    for (int nt = 0; nt < 5; ++nt)
        #pragma unroll
        for (int reg = 0; reg < 4; ++reg)
            dst[(mfrag*16 + q*4 + reg) * 160 + (ntb + nt)*16 + l16] = acc[nt][reg];
}

// ---------------- fused reduce (72 slices) + squash ----------------------
// 256 blocks (one per b) x 320 threads: kq = tid/160 in {0,1} sums 36 slices,
// coalesced across t = tid%160; LDS 2-way combine; squash; write v/out.
__global__ void __launch_bounds__(320, 2)
k_reduce_s(const float* __restrict__ s_part, float* __restrict__ vdst) {
    const int b = blockIdx.x, tid = threadIdx.x;
    const int t = tid % 160, kq = tid / 160;
    const int mt = b >> 5, bl = b & 31;
    const size_t off = (size_t)mt * 5120 + bl * 160 + t;

    float s = 0.f;
    for (int r = 0; r < 36; ++r)
        s += s_part[(size_t)(kq*36 + r) * 40960 + off];

    __shared__ float red[2][160];
    __shared__ float sv[NU];
    __shared__ float fb[UU];
    red[kq][t] = s;
    __syncthreads();
    if (tid < NU) sv[tid] = red[0][tid] + red[1][tid];
    __syncthreads();
    if (tid < UU) {
        float m = 0.f;
        #pragma unroll
        for (int n = 0; n < NN; ++n) { float z = sv[n*16 + tid]; m = fmaf(z, z, m); }
        fb[tid] = sqrtf(m) / (1.f + m);
    }
    __syncthreads();
    if (tid < NU)
        vdst[(size_t)b * NU + tid] = sv[tid] * fb[tid & 15];
}

// ---------------- pass 2a: G[nu][n'] = sum_b v[b][nu] * x[b][n'] ---------
__global__ void __launch_bounds__(256, 2)
k_vxg(const float* __restrict__ vg, const float* __restrict__ xg,
      float* __restrict__ G) {
    const int np0 = blockIdx.x * 64, m0 = blockIdx.y * 32;
    const int tid = threadIdx.x;
    const int wv = tid >> 6, lane = tid & 63;
    const int q = lane >> 4, l16 = lane & 15;

    __shared__ __align__(16) short Ash[8 * 32 * 8];
    __shared__ __align__(16) short Asl[8 * 32 * 8];
    __shared__ __align__(16) short Bsh[8 * 64 * 8];
    __shared__ __align__(16) short Bsl[8 * 64 * 8];

    f32x4 acc[2];
    acc[0] = (f32x4){0.f,0.f,0.f,0.f};
    acc[1] = (f32x4){0.f,0.f,0.f,0.f};

    for (int ks = 0; ks < 4; ++ks) {
        const int b0 = ks * 64;
        __syncthreads();
        #pragma unroll
        for (int p = 0; p < 8; ++p) {
            int idx = tid + 256 * p;
            int bb = idx >> 5, ml = idx & 31;
            float vv = vg[(size_t)(b0 + bb) * NU + m0 + ml];
            short hi = f2bf(vv);
            short lo = f2bf(vv - bf2f(hi));
            int a = ((bb >> 3) * 32 + ml) * 8 + (bb & 7);
            Ash[a] = hi; Asl[a] = lo;
        }
        #pragma unroll
        for (int p = 0; p < 16; ++p) {
            int idx = tid + 256 * p;
            int bb = idx >> 6, nl = idx & 63;
            float xv = xg[(size_t)(b0 + bb) * NP + np0 + nl];
            short hi = f2bf(xv);
            short lo = f2bf(xv - bf2f(hi));
            int a = ((bb >> 3) * 64 + nl) * 8 + (bb & 7);
            Bsh[a] = hi; Bsl[a] = lo;
        }
        __syncthreads();
        #pragma unroll
        for (int s = 0; s < 2; ++s) {
            int kc = s*4 + q;
            bf16x8 bh = *reinterpret_cast<const bf16x8*>(&Bsh[((kc*64 + wv*16 + l16) << 3)]);
            bf16x8 bl = *reinterpret_cast<const bf16x8*>(&Bsl[((kc*64 + wv*16 + l16) << 3)]);
            #pragma unroll
            for (int mtl = 0; mtl < 2; ++mtl) {
                bf16x8 ah = *reinterpret_cast<const bf16x8*>(&Ash[((kc*32 + mtl*16 + l16) << 3)]);
                bf16x8 al = *reinterpret_cast<const bf16x8*>(&Asl[((kc*32 + mtl*16 + l16) << 3)]);
                acc[mtl] = __builtin_amdgcn_mfma_f32_16x16x32_bf16(ah, bh, acc[mtl], 0, 0, 0);
                acc[mtl] = __builtin_amdgcn_mfma_f32_16x16x32_bf16(ah, bl, acc[mtl], 0, 0, 0);
                acc[mtl] = __builtin_amdgcn_mfma_f32_16x16x32_bf16(al, bh, acc[mtl], 0, 0, 0);
            }
        }
    }
    #pragma unroll
    for (int mtl = 0; mtl < 2; ++mtl)
        #pragma unroll
        for (int reg = 0; reg < 4; ++reg) {
            int m  = m0 + mtl*16 + q*4 + reg;
            G[(size_t)m * NP + np0 + wv*16 + l16] = acc[mtl][reg];
        }
}

// ---------------- pass 2b: db[j,n] = sum_{u,i} W[j,n,u,i]*G[nu][i*JC+j] --
__global__ void k_wg_db(const float* __restrict__ wg, const float* __restrict__ G,
                        float* __restrict__ db) {
    const int j0 = blockIdx.x * 64, n = blockIdx.y;
    const int tid = threadIdx.x;
    const int jl = tid & 63, up = tid >> 6;
    const int j = j0 + jl;

    const float4* wp = reinterpret_cast<const float4*>(
        wg + (size_t)j * WROW + n * 128 + up * 32);
    float acc = 0.f;
    #pragma unroll
    for (int q4 = 0; q4 < 4; ++q4) {
        int u = up*4 + q4;
        const float* gp = G + (size_t)(n*16 + u) * NP + j;
        float4 w0 = wp[q4*2], w1 = wp[q4*2 + 1];
        acc = fmaf(w0.x, gp[0*JC], acc);
        acc = fmaf(w0.y, gp[1*JC], acc);
        acc = fmaf(w0.z, gp[2*JC], acc);
        acc = fmaf(w0.w, gp[3*JC], acc);
        acc = fmaf(w1.x, gp[4*JC], acc);
        acc = fmaf(w1.y, gp[5*JC], acc);
        acc = fmaf(w1.z, gp[6*JC], acc);
        acc = fmaf(w1.w, gp[7*JC], acc);
    }
    __shared__ float red[4][64];
    red[up][jl] = acc;
    __syncthreads();
    if (tid < 64)
        db[(size_t)(j0 + tid) * NN + n] =
            red[0][tid] + red[1][tid] + red[2][tid] + red[3][tid];
}

// ---- fused: blog = blog*scale0 + db/B; c = softmax_j(blog) --------------
// scale0 = 0 on the first routing update (blog is uninitialized poison).
__global__ void k_softmax_upd(float* __restrict__ blog, const float* __restrict__ db,
                              float* __restrict__ c, float scale0) {
    int n = blockIdx.x;
    int tid = threadIdx.x;        // 256
    float myv[5]; int cnt = 0;
    for (int j = tid; j < JC; j += 256) {
        float val = blog[j*NN + n] * scale0 + db[j*NN + n] * (1.f / (float)B);
        blog[j*NN + n] = val;
        myv[cnt++] = val;
    }
    __shared__ float red[256];
    float m = -1e30f;
    for (int k = 0; k < cnt; ++k) m = fmaxf(m, myv[k]);
    red[tid] = m; __syncthreads();
    for (int s = 128; s > 0; s >>= 1) {
        if (tid < s) red[tid] = fmaxf(red[tid], red[tid+s]);
        __syncthreads();
    }
    m = red[0]; __syncthreads();
    float sum = 0.f;
    for (int k = 0; k < cnt; ++k) sum += __expf(myv[k] - m);
    red[tid] = sum; __syncthreads();
    for (int s = 128; s > 0; s >>= 1) {
        if (tid < s) red[tid] += red[tid+s];
        __syncthreads();
    }
    float inv = 1.f / red[0];
    cnt = 0;
    for (int j = tid; j < JC; j += 256)
        c[j*NN + n] = __expf(myv[cnt++] - m) * inv;
}

extern "C" void kernel_launch(void* const* d_in, const int* in_sizes, int n_in,
                              void* d_out, int out_size, void* d_ws, size_t ws_size,
                              hipStream_t stream) {
    const float* x = (const float*)d_in[0];
    const float* w = (const float*)d_in[1];
    float* out = (float*)d_out;

    float* ws     = (float*)d_ws;
    float* blog   = ws;                           // 11520
    float* c      = blog + JN;                    // 11520
    float* db     = c + JN;                       // 11520
    float* v      = db + JN;                      // 40960
    float* s_part = v + (size_t)B*NU;             // 72*40960 = 2,949,120
    float* G      = s_part + (size_t)KB * 40960;  // 1,474,560
    // total ≈ 17.9 MB

    for (int t = 0; t < 3; ++t) {
        k_gemm1<<<dim3(KB, 8), 256, 0, stream>>>(x, w, (t == 0) ? nullptr : c, s_part);
        k_reduce_s<<<B, 320, 0, stream>>>(s_part, (t == 2) ? out : v);
        if (t < 2) {
            k_vxg<<<dim3(144, 5), 256, 0, stream>>>(v, x, G);
            k_wg_db<<<dim3(18, 10), 256, 0, stream>>>(w, G, db);
            k_softmax_upd<<<NN, 256, 0, stream>>>(blog, db, c, (t == 0) ? 0.f : 1.f);
        }
    }
}